// Round 12
// baseline (200.136 us; speedup 1.0000x reference)
//
#include <hip/hip_runtime.h>

#define NXg 4096
#define NYg 4096
#define BROWS 8                 // rows per band
#define ROW0 8                  // band region covers rows [8, 4088)
#define NBANDS 510
#define NPANEL 16               // 4096 / CCOLS
#define CCOLS 256               // core cols per block
#define LCOLS 264               // 4 halo + 256 + 4 halo
#define NCHUNK 2376             // 36 rows * 66 chunks of 16B
#define NSLOTF 9728             // buffer floats: 2432 slots (56-chunk overflow pad)
#define VSLOTS 32               // vertical block slots (16 bands each; last: 14)

static constexpr float C = 10.2375f;    // Z*DT/DX = (1/400)*4095 ; DX==DY

struct F4  { float v[4];  };
struct F7  { float v[7];  };
struct F10 { float v[10]; };

__device__ __forceinline__ F4 lb4(const float* Lrow, int lc) {
    const float4 b = *(const float4*)(Lrow + lc);
    F4 x; x.v[0] = b.x; x.v[1] = b.y; x.v[2] = b.z; x.v[3] = b.w;
    return x;
}
__device__ __forceinline__ F7 l7(const float* Lrow, int lc) {
    const float4 a = *(const float4*)(Lrow + lc - 4);
    const float4 b = *(const float4*)(Lrow + lc);
    const float4 c = *(const float4*)(Lrow + lc + 4);
    F7 x;
    x.v[0] = a.w; x.v[1] = b.x; x.v[2] = b.y; x.v[3] = b.z;
    x.v[4] = b.w; x.v[5] = c.x; x.v[6] = c.y;
    return x;
}
__device__ __forceinline__ F10 l10(const float* Lrow, int lc) {
    const float4 a = *(const float4*)(Lrow + lc - 4);
    const float4 b = *(const float4*)(Lrow + lc);
    const float4 c = *(const float4*)(Lrow + lc + 4);
    F10 x;
    x.v[0] = a.y; x.v[1] = a.z; x.v[2] = a.w;
    x.v[3] = b.x; x.v[4] = b.y; x.v[5] = b.z; x.v[6] = b.w;
    x.v[7] = c.x; x.v[8] = c.y; x.v[9] = c.z;
    return x;
}
__device__ __forceinline__ F4 mid(const F7& s) {
    F4 x; x.v[0] = s.v[1]; x.v[1] = s.v[2]; x.v[2] = s.v[3]; x.v[3] = s.v[4];
    return x;
}

// ---------------------------------------------------------------------------
// Band kernel: 4-wave blocks, 8x256 tiles, double-buffered DMA, counted vmcnt.
// r9's conflict-free geometry (full-wave single-row ds_reads, 256-col core)
// + r11's pipeline (stage(next) -> vmcnt(10) -> s_barrier -> compute(cur) ->
// s_barrier -> swap). Every wave issues EXACTLY 10 global_load_lds per stage
// (waves 2,3 pad with benign duplicate loads) so vmcnt(10) is per-wave exact.
// 2 blocks/CU (76 KB LDS), persistent vertical walk of 16 bands.
// ---------------------------------------------------------------------------
__global__ __launch_bounds__(256) void band_kernel(
    const float* __restrict__ X1, const float* __restrict__ X2,
    const float* __restrict__ X3, const float* __restrict__ w1,
    float* __restrict__ E, float* __restrict__ Hx, float* __restrict__ Hy)
{
    __shared__ __attribute__((aligned(16))) float Ba[NSLOTF];
    __shared__ __attribute__((aligned(16))) float Bb[NSLOTF];

    const int tid  = threadIdx.x;           // 0..255
    const int col0 = blockIdx.x * CCOLS;
    const int k0   = blockIdx.y * 16;
    const int kend = (k0 + 16 < NBANDS) ? (k0 + 16) : NBANDS;   // v=31 -> 14 bands

    const float wv = w1[0];
    const float f0 = (wv - 1.0f) / 3.0f;
    const float f1 = -wv;
    const float f2 = wv;
    const float f3 = (1.0f - wv) / 3.0f;

    const int cq = tid & 63;                // col quad 0..63 (full wave = one row)
    const int g  = tid >> 6;                // wave id 0..3; owns rows g and g+4
    const int lc = 4 + 4 * cq;              // tile col of quad start
    const bool gL = (blockIdx.x == 0) && (cq == 0);
    const bool gR = (blockIdx.x == NPANEL - 1) && (cq == 63);

    // ---- stage: DMA one band's tile. Tile rows: 0..13 = X3[i0-3..i0+10],
    // 14..24 = X2[i0-1..i0+9], 25..35 = X1[i0-1..i0+9]; each row = 264 floats
    // = global cols [col0-4, col0+260). Chunk c (16B) -> row c/66, col4 c%66.
    // j=0..8: c = j*256+tid. j=9: waves 0,1 cover chunks 2304..2431 (clamped
    // at 2375; overflow slots 2376..2431 are write-only pad); waves 2,3
    // re-issue their j=0 chunks (same dest, same data - benign) so ALL waves
    // issue exactly 10 DMAs. Col under/overflow at panel edges reads
    // adjacent-row data (in-bounds, rows 5..4090); overridden by gL/gR fixups.
    auto stage = [&](float* lbuf, int band) {
        const int i0b = ROW0 + band * BROWS;
        #pragma unroll
        for (int j = 0; j < 10; ++j) {
            int c;
            float* lp;
            if (j == 9 && tid >= 128) {      // dummy re-issue (waves 2,3)
                c  = tid;
                lp = lbuf + (tid >> 6) * 256;
            } else {
                c  = j * 256 + tid;
                lp = lbuf + j * 1024 + (tid >> 6) * 256;
            }
            const int cc2  = (c < NCHUNK) ? c : (NCHUNK - 1);
            const int row  = cc2 / 66;
            const int col4 = cc2 - row * 66;
            const float* base = (row < 14) ? X3 : ((row < 25) ? X2 : X1);
            const int grow = i0b + ((row < 14) ? (row - 3)
                                 : ((row < 25) ? (row - 15) : (row - 26)));
            const float* gp = base + (size_t)grow * NYg + (col0 - 4) + col4 * 4;
            __builtin_amdgcn_global_load_lds(
                (const __attribute__((address_space(1))) void*)gp,
                (__attribute__((address_space(3))) void*)lp, 16, 0, 0);
        }
    };

    auto eRow4 = [&](const F4& a, const F4& b, const F4& cc, const F4& d,
                     const F10& x2r, const F4& x1r) -> F4 {
        F4 e;
        #pragma unroll
        for (int q = 0; q < 4; ++q) {
            const float e1 = x1r.v[q] + C * (cc.v[q] - b.v[q])
                                      - C * (x2r.v[q + 3] - x2r.v[q + 2]);
            e.v[q] = e1
                + C * (f0 * a.v[q] + f1 * b.v[q] + f2 * cc.v[q] + f3 * d.v[q])
                - C * (f0 * x2r.v[q + 1] + f1 * x2r.v[q + 2]
                     + f2 * x2r.v[q + 3] + f3 * x2r.v[q + 4]);
        }
        if (gL) {
            e.v[0] = x1r.v[0];
            e.v[1] = x1r.v[1] + C * (cc.v[1] - b.v[1])
                              - C * (x2r.v[4] - x2r.v[3]);
        }
        if (gR) {
            e.v[3] = x1r.v[3];
            e.v[2] = x1r.v[2] + C * (cc.v[2] - b.v[2])
                              - C * (x2r.v[5] - x2r.v[4]);
        }
        return e;
    };

    // ---- compute one output row r (0..7) of the band from the LDS tile ----
    auto computeRow = [&](const float* lb, int band, int r) {
        const int i = ROW0 + band * BROWS + r;
        const float* T3 = lb;
        const float* T2 = lb + 14 * LCOLS;
        const float* T1 = lb + 25 * LCOLS;

        const F4  x3m3 = lb4(&T3[(r    ) * LCOLS], lc);
        const F7  x3m2 = l7 (&T3[(r + 1) * LCOLS], lc);
        const F7  x3m1 = l7 (&T3[(r + 2) * LCOLS], lc);
        const F7  x3i  = l7 (&T3[(r + 3) * LCOLS], lc);
        const F7  x3p1 = l7 (&T3[(r + 4) * LCOLS], lc);
        const F4  x3p2 = lb4(&T3[(r + 5) * LCOLS], lc);
        const F4  x3p3 = lb4(&T3[(r + 6) * LCOLS], lc);

        const F10 x2m1 = l10(&T2[(r    ) * LCOLS], lc);
        const F10 x2i  = l10(&T2[(r + 1) * LCOLS], lc);
        const F10 x2p1 = l10(&T2[(r + 2) * LCOLS], lc);
        const F10 x2p2 = l10(&T2[(r + 3) * LCOLS], lc);

        const F4  x1m1 = lb4(&T1[(r    ) * LCOLS], lc);
        const F7  x1i  = l7 (&T1[(r + 1) * LCOLS], lc);
        const F4  x1p1 = lb4(&T1[(r + 2) * LCOLS], lc);
        const F4  x1p2 = lb4(&T1[(r + 3) * LCOLS], lc);

        // E row i, 7-wide
        F7 e7;
        #pragma unroll
        for (int m = 0; m < 7; ++m) {
            const float e1 = x1i.v[m] + C * (x3i.v[m] - x3m1.v[m])
                                      - C * (x2i.v[m + 2] - x2i.v[m + 1]);
            e7.v[m] = e1
                + C * (f0 * x3m2.v[m] + f1 * x3m1.v[m] + f2 * x3i.v[m] + f3 * x3p1.v[m])
                - C * (f0 * x2i.v[m] + f1 * x2i.v[m + 1] + f2 * x2i.v[m + 2] + f3 * x2i.v[m + 3]);
        }
        if (gL) {
            e7.v[1] = x1i.v[1];
            e7.v[2] = x1i.v[2] + C * (x3i.v[2] - x3m1.v[2])
                               - C * (x2i.v[4] - x2i.v[3]);
        }
        if (gR) {
            e7.v[4] = x1i.v[4];
            e7.v[3] = x1i.v[3] + C * (x3i.v[3] - x3m1.v[3])
                               - C * (x2i.v[5] - x2i.v[4]);
        }

        const F4 em1 = eRow4(x3m3,      mid(x3m2), mid(x3m1), mid(x3i), x2m1, x1m1);
        const F4 ep1 = eRow4(mid(x3m1), mid(x3i),  mid(x3p1), x3p2,     x2p1, x1p1);
        const F4 ep2 = eRow4(mid(x3i),  mid(x3p1), x3p2,      x3p3,     x2p2, x1p2);

        float hx[4], hy[4];
        #pragma unroll
        for (int q = 0; q < 4; ++q) {
            hx[q] = x2i.v[q + 3] - C * (x1i.v[q + 2] - x1i.v[q + 1])
                  - C * (f0 * e7.v[q] + f1 * e7.v[q + 1]
                       + f2 * e7.v[q + 2] + f3 * e7.v[q + 3]);
            hy[q] = x3i.v[q + 1] + C * (x1p1.v[q] - x1i.v[q + 1])
                  + C * (f0 * em1.v[q] + f1 * e7.v[q + 1]
                       + f2 * ep1.v[q] + f3 * ep2.v[q]);
        }
        if (gL) {
            hx[0] = x2i.v[3] - C * (x1i.v[2] - x1i.v[1]);
            hy[0] = x3i.v[1];
            hy[1] = x3i.v[2] + C * (x1p1.v[1] - x1i.v[2]);
        }
        if (gR) {
            hx[3] = x2i.v[6];
            hy[3] = x3i.v[4];
            hx[2] = x2i.v[5] - C * (x1i.v[4] - x1i.v[3]);
            hy[2] = x3i.v[3] + C * (x1p1.v[2] - x1i.v[3]);
        }

        const size_t idx = (size_t)i * NYg + col0 + 4 * cq;
        *(float4*)(E  + idx) = make_float4(e7.v[1], e7.v[2], e7.v[3], e7.v[4]);
        *(float4*)(Hx + idx) = make_float4(hx[0], hx[1], hx[2], hx[3]);
        *(float4*)(Hy + idx) = make_float4(hy[0], hy[1], hy[2], hy[3]);
    };

    // ---- pipeline: double-buffered, counted vmcnt, raw barriers ----
    float* cur = Ba;
    float* nxt = Bb;
    stage(cur, k0);
    for (int k = k0; k < kend; ++k) {
        if (k + 1 < kend) {
            stage(nxt, k + 1);
            // waits cur's 10 DMAs (+ old store-acks); nxt's 10 stay in flight
            asm volatile("s_waitcnt vmcnt(10)" ::: "memory");
        } else {
            asm volatile("s_waitcnt vmcnt(0)" ::: "memory");
        }
        __builtin_amdgcn_s_barrier();        // cur fully resident for all waves
        computeRow(cur, k, g);
        computeRow(cur, k, g + 4);
        asm volatile("" ::: "memory");
        __builtin_amdgcn_s_barrier();        // all reads of cur done before restage
        float* t = cur; cur = nxt; nxt = t;
    }
}

// ---------------------------------------------------------------------------
// Edge kernel: boundary row bands [0,7] and [4088,4095], fully guarded.
// ---------------------------------------------------------------------------
#define TRE 8
#define EROWSE 12
#define ECOLSE 136

__global__ __launch_bounds__(256) void edge_kernel(
    const float* __restrict__ X1, const float* __restrict__ X2,
    const float* __restrict__ X3, const float* __restrict__ w1,
    float* __restrict__ E, float* __restrict__ Hx, float* __restrict__ Hy)
{
    __shared__ float elds[EROWSE][ECOLSE];
    const int t    = threadIdx.x;
    const int row0 = blockIdx.y ? (NXg - TRE) : 0;
    const int col0 = blockIdx.x * 128;

    const float wv = w1[0];
    const float f0 = (wv - 1.0f) / 3.0f;
    const float f1 = -wv;
    const float f2 = wv;
    const float f3 = (1.0f - wv) / 3.0f;

    for (int cidx = t; cidx < EROWSE * ECOLSE; cidx += 256) {
        const int r  = cidx / ECOLSE;
        const int cc = cidx - r * ECOLSE;
        const int gr = row0 - 2 + r;
        const int gc = col0 - 4 + cc;
        float e = 0.0f;
        if (gr >= 0 && gr < NXg && gc >= 0 && gc < NYg) {
            const size_t idx = (size_t)gr * NYg + gc;
            const float x1 = X1[idx];
            if (gr == 0 || gr == NXg - 1 || gc == 0 || gc == NYg - 1) {
                e = x1;
            } else {
                float e1 = x1 + C * (X3[idx] - X3[idx - NYg])
                              - C * (X2[idx] - X2[idx - 1]);
                if (gr >= 2 && gr <= NXg - 3 && gc >= 2 && gc <= NYg - 3) {
                    e1 += C * (f0 * X3[idx - 2 * NYg] + f1 * X3[idx - NYg]
                             + f2 * X3[idx] + f3 * X3[idx + NYg])
                        - C * (f0 * X2[idx - 2] + f1 * X2[idx - 1]
                             + f2 * X2[idx] + f3 * X2[idx + 1]);
                }
                e = e1;
            }
        }
        elds[r][cc] = e;
    }
    __syncthreads();

    for (int cidx = t; cidx < TRE * 128; cidx += 256) {
        const int hr  = cidx >> 7;
        const int tc  = cidx & 127;
        const int gr  = row0 + hr;
        const int gcc = col0 + tc;
        const size_t idx = (size_t)gr * NYg + gcc;
        const int lr  = hr + 2;
        const int lc2 = tc + 4;

        const float ec = elds[lr][lc2];
        E[idx] = ec;

        const float x1 = X1[idx];

        float hx = X2[idx];
        if (gr >= 1 && gr <= NXg - 2 && gcc <= NYg - 2)
            hx -= C * (X1[idx + 1] - x1);
        if (gr >= 2 && gr <= NXg - 3 && gcc >= 1 && gcc <= NYg - 3) {
            hx -= C * (f0 * elds[lr][lc2 - 1] + f1 * ec
                     + f2 * elds[lr][lc2 + 1] + f3 * elds[lr][lc2 + 2]);
        }
        Hx[idx] = hx;

        float hy = X3[idx];
        if (gr <= NXg - 2 && gcc >= 1 && gcc <= NYg - 2)
            hy += C * (X1[idx + NYg] - x1);
        if (gr >= 1 && gr <= NXg - 3 && gcc >= 2 && gcc <= NYg - 3) {
            hy += C * (f0 * elds[lr - 1][lc2] + f1 * ec
                     + f2 * elds[lr + 1][lc2] + f3 * elds[lr + 2][lc2]);
        }
        Hy[idx] = hy;
    }
}

extern "C" void kernel_launch(void* const* d_in, const int* in_sizes, int n_in,
                              void* d_out, int out_size, void* d_ws, size_t ws_size,
                              hipStream_t stream) {
    const float* X1 = (const float*)d_in[0];
    const float* X2 = (const float*)d_in[1];
    const float* X3 = (const float*)d_in[2];
    const float* w1 = (const float*)d_in[3];

    float* E  = (float*)d_out;
    float* Hx = (float*)d_out + (size_t)NXg * NYg;
    float* Hy = (float*)d_out + 2 * (size_t)NXg * NYg;

    edge_kernel<<<dim3(32, 2), 256, 0, stream>>>(X1, X2, X3, w1, E, Hx, Hy);
    band_kernel<<<dim3(NPANEL, VSLOTS), 256, 0, stream>>>(X1, X2, X3, w1, E, Hx, Hy);
}

// Round 13
// 141.065 us; speedup vs baseline: 1.4187x; 1.4187x over previous
//
#include <hip/hip_runtime.h>

#define NXg 4096
#define NYg 4096
#define ROW0 8                 // row kernel covers rows [8, 4087]
#define NROWS 4080

static constexpr float C = 10.2375f;   // Z*DT/DX = (1/400)*4095 ; DX==DY

struct F4  { float v[4];  };   // cols c0   .. c0+3
struct F7  { float v[7];  };   // cols c0-1 .. c0+5
struct F10 { float v[10]; };   // cols c0-3 .. c0+6

// Load 12 consecutive floats at row r, cols c0-4 .. c0+7 (three aligned float4).
// In-bounds for rows in [5, 4090]. At col edges the outer float4s contain
// neighboring-row data; consumed only by lanes whose results are overridden
// by gL/gR fixups.
__device__ __forceinline__ void ld12(const float* __restrict__ P, int r, int c0,
                                     float4& a, float4& b, float4& c) {
    const size_t o = (size_t)r * NYg + c0;
    a = *(const float4*)(P + o - 4);
    b = *(const float4*)(P + o);
    c = *(const float4*)(P + o + 4);
}
__device__ __forceinline__ F7 ld7(const float* __restrict__ P, int r, int c0) {
    float4 a, b, c; ld12(P, r, c0, a, b, c);
    F7 x;
    x.v[0] = a.w; x.v[1] = b.x; x.v[2] = b.y; x.v[3] = b.z;
    x.v[4] = b.w; x.v[5] = c.x; x.v[6] = c.y;
    return x;
}
__device__ __forceinline__ F10 ld10(const float* __restrict__ P, int r, int c0) {
    float4 a, b, c; ld12(P, r, c0, a, b, c);
    F10 x;
    x.v[0] = a.y; x.v[1] = a.z; x.v[2] = a.w;
    x.v[3] = b.x; x.v[4] = b.y; x.v[5] = b.z; x.v[6] = b.w;
    x.v[7] = c.x; x.v[8] = c.y; x.v[9] = c.z;
    return x;
}
__device__ __forceinline__ F4 ldb(const float* __restrict__ P, int r, int c0) {
    const float4 b = *(const float4*)(P + (size_t)r * NYg + c0);
    F4 x; x.v[0] = b.x; x.v[1] = b.y; x.v[2] = b.z; x.v[3] = b.w;
    return x;
}
__device__ __forceinline__ F4 mid(const F7& s) {   // cols c0..c0+3 of a F7
    F4 x; x.v[0] = s.v[1]; x.v[1] = s.v[2]; x.v[2] = s.v[3]; x.v[3] = s.v[4];
    return x;
}

// ---------------------------------------------------------------------------
// Row kernel (r7 structure + r8 mechanism): one thread = one row x 4 cols.
// All 33 float4 loads are independent straight-line code; the
// sched_barrier(0) after them forbids the scheduler's load-sinking (r7: VGPR
// collapsed to 64, MLP ~1.5; r8 proved the barrier un-sinks: VGPR 68->108).
// launch_bounds(256,2) gives the 256-VGPR budget the pinned loads need.
// No LDS, no barriers (r9-r12's LDS staging paid an unfixable read-side tax).
// ---------------------------------------------------------------------------
__global__ __launch_bounds__(256, 2) void row_kernel(
    const float* __restrict__ X1, const float* __restrict__ X2,
    const float* __restrict__ X3, const float* __restrict__ w1,
    float* __restrict__ E, float* __restrict__ Hx, float* __restrict__ Hy)
{
    const int t  = threadIdx.x;
    const int c0 = (blockIdx.x * 256 + t) * 4;
    const int i  = ROW0 + blockIdx.y;        // output row, in [8, 4087]
    const bool gL = (c0 == 0);
    const bool gR = (c0 == NYg - 4);

    const float wv = w1[0];
    const float f0 = (wv - 1.0f) / 3.0f;
    const float f1 = -wv;
    const float f2 = wv;
    const float f3 = (1.0f - wv) / 3.0f;

    // ---------------- loads (rows i-3 .. i+3, all in [5, 4090]) ----------------
    const F4  x3m3 = ldb(X3, i - 3, c0);
    const F7  x3m2 = ld7(X3, i - 2, c0);
    const F7  x3m1 = ld7(X3, i - 1, c0);
    const F7  x3i  = ld7(X3, i,     c0);
    const F7  x3p1 = ld7(X3, i + 1, c0);
    const F4  x3p2 = ldb(X3, i + 2, c0);
    const F4  x3p3 = ldb(X3, i + 3, c0);

    const F10 x2m1 = ld10(X2, i - 1, c0);
    const F10 x2i  = ld10(X2, i,     c0);
    const F10 x2p1 = ld10(X2, i + 1, c0);
    const F10 x2p2 = ld10(X2, i + 2, c0);

    const F4  x1m1 = ldb(X1, i - 1, c0);
    const F7  x1i  = ld7(X1, i,     c0);
    const F4  x1p1 = ldb(X1, i + 1, c0);
    const F4  x1p2 = ldb(X1, i + 2, c0);

    // pin: all 33 loads issue before any compute (defeats load-sinking)
    __builtin_amdgcn_sched_barrier(0);

    // ---------------- E row i, 7-wide (cols c0-1 .. c0+5) ----------------
    F7 e7;
    #pragma unroll
    for (int m = 0; m < 7; ++m) {
        const float e1 = x1i.v[m] + C * (x3i.v[m] - x3m1.v[m])
                                  - C * (x2i.v[m + 2] - x2i.v[m + 1]);
        e7.v[m] = e1
            + C * (f0 * x3m2.v[m] + f1 * x3m1.v[m] + f2 * x3i.v[m] + f3 * x3p1.v[m])
            - C * (f0 * x2i.v[m] + f1 * x2i.v[m + 1] + f2 * x2i.v[m + 2] + f3 * x2i.v[m + 3]);
    }
    if (gL) {
        e7.v[1] = x1i.v[1];                                     // j=0: copy
        e7.v[2] = x1i.v[2] + C * (x3i.v[2] - x3m1.v[2])
                           - C * (x2i.v[4] - x2i.v[3]);         // j=1: BC only
    }
    if (gR) {
        e7.v[4] = x1i.v[4];                                     // j=4095: copy
        e7.v[3] = x1i.v[3] + C * (x3i.v[3] - x3m1.v[3])
                           - C * (x2i.v[5] - x2i.v[4]);         // j=4094: BC only
    }

    // ---------------- E rows i-1, i+1, i+2, 4-wide (cols c0..c0+3) ----------------
    auto eRow4 = [&](const F4& a, const F4& b, const F4& cc, const F4& d,
                     const F10& x2r, const F4& x1r) -> F4 {
        F4 e;
        #pragma unroll
        for (int q = 0; q < 4; ++q) {
            const float e1 = x1r.v[q] + C * (cc.v[q] - b.v[q])
                                      - C * (x2r.v[q + 3] - x2r.v[q + 2]);
            e.v[q] = e1
                + C * (f0 * a.v[q] + f1 * b.v[q] + f2 * cc.v[q] + f3 * d.v[q])
                - C * (f0 * x2r.v[q + 1] + f1 * x2r.v[q + 2]
                     + f2 * x2r.v[q + 3] + f3 * x2r.v[q + 4]);
        }
        if (gL) {
            e.v[0] = x1r.v[0];                                  // j=0: copy
            e.v[1] = x1r.v[1] + C * (cc.v[1] - b.v[1])
                              - C * (x2r.v[4] - x2r.v[3]);      // j=1: BC only
        }
        if (gR) {
            e.v[3] = x1r.v[3];                                  // j=4095: copy
            e.v[2] = x1r.v[2] + C * (cc.v[2] - b.v[2])
                              - C * (x2r.v[5] - x2r.v[4]);      // j=4094: BC only
        }
        return e;
    };

    const F4 em1 = eRow4(x3m3,      mid(x3m2), mid(x3m1), mid(x3i), x2m1, x1m1);
    const F4 ep1 = eRow4(mid(x3m1), mid(x3i),  mid(x3p1), x3p2,     x2p1, x1p1);
    const F4 ep2 = eRow4(mid(x3i),  mid(x3p1), x3p2,      x3p3,     x2p2, x1p2);

    // ---------------- outputs ----------------
    float hx[4], hy[4];
    #pragma unroll
    for (int q = 0; q < 4; ++q) {
        hx[q] = x2i.v[q + 3] - C * (x1i.v[q + 2] - x1i.v[q + 1])
              - C * (f0 * e7.v[q] + f1 * e7.v[q + 1]
                   + f2 * e7.v[q + 2] + f3 * e7.v[q + 3]);
        hy[q] = x3i.v[q + 1] + C * (x1p1.v[q] - x1i.v[q + 1])
              + C * (f0 * em1.v[q] + f1 * e7.v[q + 1]
                   + f2 * ep1.v[q] + f3 * ep2.v[q]);
    }
    if (gL) {
        hx[0] = x2i.v[3] - C * (x1i.v[2] - x1i.v[1]);           // j=0: no f4
        hy[0] = x3i.v[1];                                       // j=0: copy X3
        hy[1] = x3i.v[2] + C * (x1p1.v[1] - x1i.v[2]);          // j=1: no f4
    }
    if (gR) {
        hx[3] = x2i.v[6];                                       // j=4095: copy X2
        hy[3] = x3i.v[4];                                       // j=4095: copy X3
        hx[2] = x2i.v[5] - C * (x1i.v[4] - x1i.v[3]);           // j=4094: no f4
        hy[2] = x3i.v[3] + C * (x1p1.v[2] - x1i.v[3]);          // j=4094: no f4
    }

    const size_t idx = (size_t)i * NYg + c0;
    *(float4*)(E  + idx) = make_float4(e7.v[1], e7.v[2], e7.v[3], e7.v[4]);
    *(float4*)(Hx + idx) = make_float4(hx[0], hx[1], hx[2], hx[3]);
    *(float4*)(Hy + idx) = make_float4(hy[0], hy[1], hy[2], hy[3]);
}

// ---------------------------------------------------------------------------
// Edge kernel: boundary row bands [0,7] and [4088,4095], fully guarded.
// ---------------------------------------------------------------------------
#define TRE 8
#define EROWSE 12
#define ECOLSE 136

__global__ __launch_bounds__(256) void edge_kernel(
    const float* __restrict__ X1, const float* __restrict__ X2,
    const float* __restrict__ X3, const float* __restrict__ w1,
    float* __restrict__ E, float* __restrict__ Hx, float* __restrict__ Hy)
{
    __shared__ float elds[EROWSE][ECOLSE];
    const int t    = threadIdx.x;
    const int row0 = blockIdx.y ? (NXg - TRE) : 0;
    const int col0 = blockIdx.x * 128;

    const float wv = w1[0];
    const float f0 = (wv - 1.0f) / 3.0f;
    const float f1 = -wv;
    const float f2 = wv;
    const float f3 = (1.0f - wv) / 3.0f;

    for (int cidx = t; cidx < EROWSE * ECOLSE; cidx += 256) {
        const int r  = cidx / ECOLSE;
        const int cc = cidx - r * ECOLSE;
        const int gr = row0 - 2 + r;
        const int gc = col0 - 4 + cc;
        float e = 0.0f;
        if (gr >= 0 && gr < NXg && gc >= 0 && gc < NYg) {
            const size_t idx = (size_t)gr * NYg + gc;
            const float x1 = X1[idx];
            if (gr == 0 || gr == NXg - 1 || gc == 0 || gc == NYg - 1) {
                e = x1;
            } else {
                float e1 = x1 + C * (X3[idx] - X3[idx - NYg])
                              - C * (X2[idx] - X2[idx - 1]);
                if (gr >= 2 && gr <= NXg - 3 && gc >= 2 && gc <= NYg - 3) {
                    e1 += C * (f0 * X3[idx - 2 * NYg] + f1 * X3[idx - NYg]
                             + f2 * X3[idx] + f3 * X3[idx + NYg])
                        - C * (f0 * X2[idx - 2] + f1 * X2[idx - 1]
                             + f2 * X2[idx] + f3 * X2[idx + 1]);
                }
                e = e1;
            }
        }
        elds[r][cc] = e;
    }
    __syncthreads();

    for (int cidx = t; cidx < TRE * 128; cidx += 256) {
        const int hr  = cidx >> 7;
        const int tc  = cidx & 127;
        const int gr  = row0 + hr;
        const int gcc = col0 + tc;
        const size_t idx = (size_t)gr * NYg + gcc;
        const int lr  = hr + 2;
        const int lc2 = tc + 4;

        const float ec = elds[lr][lc2];
        E[idx] = ec;

        const float x1 = X1[idx];

        float hx = X2[idx];
        if (gr >= 1 && gr <= NXg - 2 && gcc <= NYg - 2)
            hx -= C * (X1[idx + 1] - x1);
        if (gr >= 2 && gr <= NXg - 3 && gcc >= 1 && gcc <= NYg - 3) {
            hx -= C * (f0 * elds[lr][lc2 - 1] + f1 * ec
                     + f2 * elds[lr][lc2 + 1] + f3 * elds[lr][lc2 + 2]);
        }
        Hx[idx] = hx;

        float hy = X3[idx];
        if (gr <= NXg - 2 && gcc >= 1 && gcc <= NYg - 2)
            hy += C * (X1[idx + NYg] - x1);
        if (gr >= 1 && gr <= NXg - 3 && gcc >= 2 && gcc <= NYg - 3) {
            hy += C * (f0 * elds[lr - 1][lc2] + f1 * ec
                     + f2 * elds[lr + 1][lc2] + f3 * elds[lr + 2][lc2]);
        }
        Hy[idx] = hy;
    }
}

extern "C" void kernel_launch(void* const* d_in, const int* in_sizes, int n_in,
                              void* d_out, int out_size, void* d_ws, size_t ws_size,
                              hipStream_t stream) {
    const float* X1 = (const float*)d_in[0];
    const float* X2 = (const float*)d_in[1];
    const float* X3 = (const float*)d_in[2];
    const float* w1 = (const float*)d_in[3];

    float* E  = (float*)d_out;
    float* Hx = (float*)d_out + (size_t)NXg * NYg;
    float* Hy = (float*)d_out + 2 * (size_t)NXg * NYg;

    edge_kernel<<<dim3(32, 2), 256, 0, stream>>>(X1, X2, X3, w1, E, Hx, Hy);
    row_kernel <<<dim3(NYg / 1024, NROWS), 256, 0, stream>>>(X1, X2, X3, w1, E, Hx, Hy);
}

// Round 14
// 103.025 us; speedup vs baseline: 1.9426x; 1.3692x over previous
//
#include <hip/hip_runtime.h>

#define NXg 4096
#define NYg 4096
#define RPT 8                  // output rows per thread (fat kernel)
#define ROW0 8                 // fat kernel covers rows [8, 4087]
#define NBANDS 510             // (4088-8)/RPT
#define BTHREADS 128           // threads per block (2 waves); block covers 512 cols

static constexpr float C = 10.2375f;   // Z*DT/DX = (1/400)*4095 ; DX==DY

struct F7  { float v[7];  };   // cols c0-1 .. c0+5
struct F10 { float v[10]; };   // cols c0-3 .. c0+6

// Load 12 consecutive floats at row r, cols c0-4 .. c0+7 (three aligned float4).
// Memory-safe for all rows used here (r in [5, 4091]); col under/overflow at
// panel edges reads adjacent-row data, consumed only by lanes overridden by
// the gL/gR fixups.
__device__ __forceinline__ void ld12(const float* __restrict__ P, int r, int c0,
                                     float4& a, float4& b, float4& c) {
    const size_t o = (size_t)r * NYg + c0;
    a = *(const float4*)(P + o - 4);
    b = *(const float4*)(P + o);
    c = *(const float4*)(P + o + 4);
}

__device__ __forceinline__ F7 mk7(const float4& a, const float4& b, const float4& c) {
    F7 r;
    r.v[0] = a.w; r.v[1] = b.x; r.v[2] = b.y; r.v[3] = b.z;
    r.v[4] = b.w; r.v[5] = c.x; r.v[6] = c.y;
    return r;
}
__device__ __forceinline__ F10 mk10(const float4& a, const float4& b, const float4& c) {
    F10 r;
    r.v[0] = a.y; r.v[1] = a.z; r.v[2] = a.w;
    r.v[3] = b.x; r.v[4] = b.y; r.v[5] = b.z; r.v[6] = b.w;
    r.v[7] = c.x; r.v[8] = c.y; r.v[9] = c.z;
    return r;
}

__device__ __forceinline__ F7 ld7(const float* __restrict__ P, int r, int c0) {
    float4 a, b, c; ld12(P, r, c0, a, b, c); return mk7(a, b, c);
}
__device__ __forceinline__ F10 ld10(const float* __restrict__ P, int r, int c0) {
    float4 a, b, c; ld12(P, r, c0, a, b, c); return mk10(a, b, c);
}

// ---------------------------------------------------------------------------
// Fat kernel (r8 base + DEPTH-2 prefetch): rows [8, 4087]. Thread owns cols
// c0..c0+3, walks RPT rows with rolling register windows; E computed 7-wide.
//
// r8 (depth-1): roll consumes the NEWEST loads -> compiler emits ~vmcnt(0),
// wave stalls ~latency-compute each iteration. Depth-2: iteration s issues
// G(i+1) while the roll consumes G(i) (issued one iteration earlier, 9 newer
// loads outstanding) -> compiler emits vmcnt(9); stall ~= latency - 2*compute.
// stg[2] indexed by s&1 inside a fully-unrolled loop = static indexing.
// r13 lesson: sched_barrier pins work ONLY with consumption deferred across
// an iteration (r8 VGPR 108) — straight-line pins get re-serialized (r13: 60).
// ---------------------------------------------------------------------------
__global__ __launch_bounds__(BTHREADS, 2) void fat_kernel(
    const float* __restrict__ X1, const float* __restrict__ X2,
    const float* __restrict__ X3, const float* __restrict__ w1,
    float* __restrict__ E, float* __restrict__ Hx, float* __restrict__ Hy)
{
    const int t  = threadIdx.x;
    const int c0 = (blockIdx.x * BTHREADS + t) * 4;
    const int i0 = ROW0 + blockIdx.y * RPT;
    const bool gL = (c0 == 0);
    const bool gR = (c0 == NYg - 4);

    const float wv = w1[0];
    const float f0 = (wv - 1.0f) / 3.0f;
    const float f1 = -wv;
    const float f2 = wv;
    const float f3 = (1.0f - wv) / 3.0f;

    auto eRow = [&](const F7& x3m2, const F7& x3m1, const F7& x3p0, const F7& x3p1,
                    const F10& x2r, const F7& x1r) -> F7 {
        F7 e;
        #pragma unroll
        for (int m = 0; m < 7; ++m) {
            const float e1 = x1r.v[m] + C * (x3p0.v[m] - x3m1.v[m])
                                      - C * (x2r.v[m + 2] - x2r.v[m + 1]);
            e.v[m] = e1
                + C * (f0 * x3m2.v[m] + f1 * x3m1.v[m] + f2 * x3p0.v[m] + f3 * x3p1.v[m])
                - C * (f0 * x2r.v[m] + f1 * x2r.v[m + 1] + f2 * x2r.v[m + 2] + f3 * x2r.v[m + 3]);
        }
        if (gL) {
            e.v[1] = x1r.v[1];                                  // j=0: copy
            e.v[2] = x1r.v[2] + C * (x3p0.v[2] - x3m1.v[2])
                              - C * (x2r.v[4] - x2r.v[3]);      // j=1: BC only
        }
        if (gR) {
            e.v[4] = x1r.v[4];                                  // j=4095: copy
            e.v[3] = x1r.v[3] + C * (x3p0.v[3] - x3m1.v[3])
                              - C * (x2r.v[5] - x2r.v[4]);      // j=4094: BC only
        }
        return e;
    };

    // ---------------- Prologue: fill windows for i = i0 ----------------
    F7 p3a = ld7(X3, i0 - 3, c0);
    F7 p3b = ld7(X3, i0 - 2, c0);
    F7 p3c = ld7(X3, i0 - 1, c0);
    F7 w3[4];
    w3[0] = ld7(X3, i0,     c0);
    w3[1] = ld7(X3, i0 + 1, c0);
    w3[2] = ld7(X3, i0 + 2, c0);
    w3[3] = ld7(X3, i0 + 3, c0);

    F10 q2a = ld10(X2, i0 - 1, c0);
    F10 q2b = ld10(X2, i0,     c0);
    F10 q2c = ld10(X2, i0 + 1, c0);
    F10 w2r = ld10(X2, i0 + 2, c0);   // X2 row i+2

    F7 q1a = ld7(X1, i0 - 1, c0);
    F7 w1r[3];
    w1r[0] = ld7(X1, i0,     c0);
    w1r[1] = ld7(X1, i0 + 1, c0);
    w1r[2] = ld7(X1, i0 + 2, c0);

    // depth-2 staging set 0: G(i0) = rows consumed at iter s=0's roll
    F7  stg3[2]; F10 stg2[2]; F7 stg1[2];
    stg3[0] = ld7 (X3, i0 + 4, c0);
    stg2[0] = ld10(X2, i0 + 3, c0);
    stg1[0] = ld7 (X1, i0 + 3, c0);

    // pin: all prologue loads issued before any compute
    __builtin_amdgcn_sched_barrier(0);

    F7 ew[4];                          // E rows i-1 .. i+2
    ew[0] = eRow(p3a, p3b, p3c, w3[0], q2a, q1a);        // E[i0-1]
    ew[1] = eRow(p3b, p3c, w3[0], w3[1], q2b, w1r[0]);   // E[i0]
    ew[2] = eRow(p3c, w3[0], w3[1], w3[2], q2c, w1r[1]); // E[i0+1]

    float x2c0[4] = {q2b.v[3], q2b.v[4], q2b.v[5], q2b.v[6]};  // X2[i] centers
    float x2c1[4] = {q2c.v[3], q2c.v[4], q2c.v[5], q2c.v[6]};  // X2[i+1] centers

    // ---------------- Main loop over output rows ----------------
    #pragma unroll
    for (int s = 0; s < RPT; ++s) {
        const int i   = i0 + s;
        const int cur = s & 1;         // compile-time (loop fully unrolled)
        const int nxt = cur ^ 1;

        // issue G(i+1): rows consumed at iter s+1's roll (2 iterations of
        // latency hiding for each group). Guarded only by s — rows stay
        // memory-safe (max X3 row i0+11 <= 4091).
        if (s < RPT - 2) {
            stg3[nxt] = ld7 (X3, i + 5, c0);
            stg2[nxt] = ld10(X2, i + 4, c0);
            stg1[nxt] = ld7 (X1, i + 4, c0);
        }
        // pin: this iteration's 9 prefetch loads stay in flight across compute
        __builtin_amdgcn_sched_barrier(0);

        // E row i+2 from already-resident windows
        ew[3] = eRow(w3[0], w3[1], w3[2], w3[3], w2r, w1r[2]);

        // ---- outputs for row i ----
        float hx[4], hy[4];
        #pragma unroll
        for (int q = 0; q < 4; ++q) {
            hx[q] = x2c0[q] - C * (w1r[0].v[q + 2] - w1r[0].v[q + 1])
                  - C * (f0 * ew[1].v[q]     + f1 * ew[1].v[q + 1]
                       + f2 * ew[1].v[q + 2] + f3 * ew[1].v[q + 3]);
            hy[q] = w3[0].v[q + 1] + C * (w1r[1].v[q + 1] - w1r[0].v[q + 1])
                  + C * (f0 * ew[0].v[q + 1] + f1 * ew[1].v[q + 1]
                       + f2 * ew[2].v[q + 1] + f3 * ew[3].v[q + 1]);
        }
        if (gL) {
            hx[0] = x2c0[0] - C * (w1r[0].v[2] - w1r[0].v[1]);    // j=0: no f4
            hy[0] = w3[0].v[1];                                   // j=0: copy X3
            hy[1] = w3[0].v[2] + C * (w1r[1].v[2] - w1r[0].v[2]); // j=1: no f4
        }
        if (gR) {
            hx[3] = x2c0[3];                                      // j=4095: copy X2
            hy[3] = w3[0].v[4];                                   // j=4095: copy X3
            hx[2] = x2c0[2] - C * (w1r[0].v[4] - w1r[0].v[3]);    // j=4094: no f4
            hy[2] = w3[0].v[3] + C * (w1r[1].v[3] - w1r[0].v[3]); // j=4094: no f4
        }

        const size_t idx = (size_t)i * NYg + c0;
        *(float4*)(E  + idx) = make_float4(ew[1].v[1], ew[1].v[2], ew[1].v[3], ew[1].v[4]);
        *(float4*)(Hx + idx) = make_float4(hx[0], hx[1], hx[2], hx[3]);
        *(float4*)(Hy + idx) = make_float4(hy[0], hy[1], hy[2], hy[3]);

        // ---- roll windows; consume G(i) (9 newer loads outstanding ->
        // compiler emits vmcnt(9), not vmcnt(0)) ----
        ew[0] = ew[1]; ew[1] = ew[2]; ew[2] = ew[3];
        w3[0] = w3[1]; w3[1] = w3[2]; w3[2] = w3[3];
        w1r[0] = w1r[1]; w1r[1] = w1r[2];
        #pragma unroll
        for (int q = 0; q < 4; ++q) { x2c0[q] = x2c1[q]; x2c1[q] = w2r.v[3 + q]; }
        if (s < RPT - 1) {
            w3[3]  = stg3[cur];
            w2r    = stg2[cur];
            w1r[2] = stg1[cur];
        }
    }
}

// ---------------------------------------------------------------------------
// Edge kernel: boundary row bands [0,7] and [4088,4095], fully guarded.
// ---------------------------------------------------------------------------
#define TRE 8
#define EROWSE 12
#define ECOLSE 136

__global__ __launch_bounds__(256) void edge_kernel(
    const float* __restrict__ X1, const float* __restrict__ X2,
    const float* __restrict__ X3, const float* __restrict__ w1,
    float* __restrict__ E, float* __restrict__ Hx, float* __restrict__ Hy)
{
    __shared__ float elds[EROWSE][ECOLSE];
    const int t    = threadIdx.x;
    const int row0 = blockIdx.y ? (NXg - TRE) : 0;
    const int col0 = blockIdx.x * 128;

    const float wv = w1[0];
    const float f0 = (wv - 1.0f) / 3.0f;
    const float f1 = -wv;
    const float f2 = wv;
    const float f3 = (1.0f - wv) / 3.0f;

    for (int cidx = t; cidx < EROWSE * ECOLSE; cidx += 256) {
        const int r  = cidx / ECOLSE;
        const int cc = cidx - r * ECOLSE;
        const int gr = row0 - 2 + r;
        const int gc = col0 - 4 + cc;
        float e = 0.0f;
        if (gr >= 0 && gr < NXg && gc >= 0 && gc < NYg) {
            const size_t idx = (size_t)gr * NYg + gc;
            const float x1 = X1[idx];
            if (gr == 0 || gr == NXg - 1 || gc == 0 || gc == NYg - 1) {
                e = x1;
            } else {
                float e1 = x1 + C * (X3[idx] - X3[idx - NYg])
                              - C * (X2[idx] - X2[idx - 1]);
                if (gr >= 2 && gr <= NXg - 3 && gc >= 2 && gc <= NYg - 3) {
                    e1 += C * (f0 * X3[idx - 2 * NYg] + f1 * X3[idx - NYg]
                             + f2 * X3[idx] + f3 * X3[idx + NYg])
                        - C * (f0 * X2[idx - 2] + f1 * X2[idx - 1]
                             + f2 * X2[idx] + f3 * X2[idx + 1]);
                }
                e = e1;
            }
        }
        elds[r][cc] = e;
    }
    __syncthreads();

    for (int cidx = t; cidx < TRE * 128; cidx += 256) {
        const int hr  = cidx >> 7;
        const int tc  = cidx & 127;
        const int gr  = row0 + hr;
        const int gcc = col0 + tc;
        const size_t idx = (size_t)gr * NYg + gcc;
        const int lr  = hr + 2;
        const int lc2 = tc + 4;

        const float ec = elds[lr][lc2];
        E[idx] = ec;

        const float x1 = X1[idx];

        float hx = X2[idx];
        if (gr >= 1 && gr <= NXg - 2 && gcc <= NYg - 2)
            hx -= C * (X1[idx + 1] - x1);
        if (gr >= 2 && gr <= NXg - 3 && gcc >= 1 && gcc <= NYg - 3) {
            hx -= C * (f0 * elds[lr][lc2 - 1] + f1 * ec
                     + f2 * elds[lr][lc2 + 1] + f3 * elds[lr][lc2 + 2]);
        }
        Hx[idx] = hx;

        float hy = X3[idx];
        if (gr <= NXg - 2 && gcc >= 1 && gcc <= NYg - 2)
            hy += C * (X1[idx + NYg] - x1);
        if (gr >= 1 && gr <= NXg - 3 && gcc >= 2 && gcc <= NYg - 3) {
            hy += C * (f0 * elds[lr - 1][lc2] + f1 * ec
                     + f2 * elds[lr + 1][lc2] + f3 * elds[lr + 2][lc2]);
        }
        Hy[idx] = hy;
    }
}

extern "C" void kernel_launch(void* const* d_in, const int* in_sizes, int n_in,
                              void* d_out, int out_size, void* d_ws, size_t ws_size,
                              hipStream_t stream) {
    const float* X1 = (const float*)d_in[0];
    const float* X2 = (const float*)d_in[1];
    const float* X3 = (const float*)d_in[2];
    const float* w1 = (const float*)d_in[3];

    float* E  = (float*)d_out;
    float* Hx = (float*)d_out + (size_t)NXg * NYg;
    float* Hy = (float*)d_out + 2 * (size_t)NXg * NYg;

    edge_kernel<<<dim3(32, 2), 256, 0, stream>>>(X1, X2, X3, w1, E, Hx, Hy);
    fat_kernel <<<dim3(NYg / (BTHREADS * 4), NBANDS), BTHREADS, 0, stream>>>(
        X1, X2, X3, w1, E, Hx, Hy);
}

// Round 15
// 98.594 us; speedup vs baseline: 2.0299x; 1.0450x over previous
//
#include <hip/hip_runtime.h>

#define NXg 4096
#define NYg 4096
#define BROWS 12                // output rows per band
#define ROW0 8                  // band region covers rows [8, 4088)
#define NBANDS 340              // 4080 / 12
#define NPANEL 16               // 4096 / CCOLS
#define CCOLS 256               // core cols per block
#define LCOLS 264               // 4 halo + 256 + 4 halo
#define R3 18                   // X3 tile rows: i0-3 .. i0+14
#define R2 15                   // X2 tile rows: i0-1 .. i0+13
#define R1 15                   // X1 tile rows: i0-1 .. i0+13
#define CPR 66                  // 16B chunks per tile row
#define NCHUNK 3168             // 48 rows * 66
#define NJ 13                   // DMA iters: 13*256 = 3328 >= 3168
#define NSLOTF 13312            // 3328 chunk slots * 4 floats (incl. pad)

static constexpr float C = 10.2375f;    // Z*DT/DX = (1/400)*4095 ; DX==DY

struct F4  { float v[4];  };
struct F7  { float v[7];  };
struct F10 { float v[10]; };

__device__ __forceinline__ F4 lb4(const float* Lrow, int lc) {
    const float4 b = *(const float4*)(Lrow + lc);
    F4 x; x.v[0] = b.x; x.v[1] = b.y; x.v[2] = b.z; x.v[3] = b.w;
    return x;
}
__device__ __forceinline__ F7 l7(const float* Lrow, int lc) {
    const float4 a = *(const float4*)(Lrow + lc - 4);
    const float4 b = *(const float4*)(Lrow + lc);
    const float4 c = *(const float4*)(Lrow + lc + 4);
    F7 x;
    x.v[0] = a.w; x.v[1] = b.x; x.v[2] = b.y; x.v[3] = b.z;
    x.v[4] = b.w; x.v[5] = c.x; x.v[6] = c.y;
    return x;
}
__device__ __forceinline__ F10 l10(const float* Lrow, int lc) {
    const float4 a = *(const float4*)(Lrow + lc - 4);
    const float4 b = *(const float4*)(Lrow + lc);
    const float4 c = *(const float4*)(Lrow + lc + 4);
    F10 x;
    x.v[0] = a.y; x.v[1] = a.z; x.v[2] = a.w;
    x.v[3] = b.x; x.v[4] = b.y; x.v[5] = b.z; x.v[6] = b.w;
    x.v[7] = c.x; x.v[8] = c.y; x.v[9] = c.z;
    return x;
}
__device__ __forceinline__ F4 mid(const F7& s) {
    F4 x; x.v[0] = s.v[1]; x.v[1] = s.v[2]; x.v[2] = s.v[3]; x.v[3] = s.v[4];
    return x;
}

// ---------------------------------------------------------------------------
// Band kernel: r9's proven one-band-per-block DMA structure with BROWS 8->12
// (stage redundancy 4.5x -> 4.0x) and 256 threads (3 blocks/CU = 12 waves/CU,
// vs r9's 8). stage -> __syncthreads -> compute -> exit; latency hiding comes
// from 3 co-resident blocks in staggered phases (what made r9 the best
// measured structure; r10-r12's intra-block pipelines all regressed).
// ---------------------------------------------------------------------------
__global__ __launch_bounds__(256) void band_kernel(
    const float* __restrict__ X1, const float* __restrict__ X2,
    const float* __restrict__ X3, const float* __restrict__ w1,
    float* __restrict__ E, float* __restrict__ Hx, float* __restrict__ Hy)
{
    __shared__ __attribute__((aligned(16))) float B[NSLOTF];

    const int tid  = threadIdx.x;           // 0..255
    const int col0 = blockIdx.x * CCOLS;
    const int i0   = ROW0 + blockIdx.y * BROWS;

    const float wv = w1[0];
    const float f0 = (wv - 1.0f) / 3.0f;
    const float f1 = -wv;
    const float f2 = wv;
    const float f3 = (1.0f - wv) / 3.0f;

    const int cq = tid & 63;                // col quad 0..63 (full wave = one row)
    const int g  = tid >> 6;                // wave id 0..3; owns rows g, g+4, g+8
    const int lc = 4 + 4 * cq;
    const bool gL = (blockIdx.x == 0) && (cq == 0);
    const bool gR = (blockIdx.x == NPANEL - 1) && (cq == 63);

    // ---- stage: DMA the band's tile. Tile rows 0..17 = X3[i0-3..i0+14],
    // 18..32 = X2[i0-1..i0+13], 33..47 = X1[i0-1..i0+13]; each row = 264
    // floats = global cols [col0-4, col0+260). Chunk c -> slot c (dest =
    // wave-uniform base + lane*16, slot index = j*256 + wave*64 + lane).
    // Chunks >= NCHUNK clamp the SOURCE to chunk NCHUNK-1 and land in the
    // pad slots 3168..3327 (write-only). Global rows span [i0-3, i0+14] in
    // [5, 4090] -> col +/-4 overflow reads adjacent rows, always in-bounds;
    // consumed only by lanes overridden by the gL/gR fixups.
    {
        #pragma unroll
        for (int j = 0; j < NJ; ++j) {
            const int c    = j * 256 + tid;
            const int cc2  = (c < NCHUNK) ? c : (NCHUNK - 1);
            const int row  = cc2 / CPR;
            const int col4 = cc2 - row * CPR;
            const float* base = (row < R3) ? X3 : ((row < R3 + R2) ? X2 : X1);
            const int grow = i0 + ((row < R3) ? (row - 3)
                                 : ((row < R3 + R2) ? (row - R3 - 1)
                                                    : (row - R3 - R2 - 1)));
            const float* gp = base + (size_t)grow * NYg + (col0 - 4) + col4 * 4;
            float* lp = B + j * 1024 + (tid >> 6) * 256;   // wave-uniform base
            __builtin_amdgcn_global_load_lds(
                (const __attribute__((address_space(1))) void*)gp,
                (__attribute__((address_space(3))) void*)lp, 16, 0, 0);
        }
    }
    __syncthreads();   // drain DMA (vmcnt 0) + barrier — r9's proven shape

    const float* T3 = B;                     // 18 rows
    const float* T2 = B + R3 * LCOLS;        // 15 rows
    const float* T1 = B + (R3 + R2) * LCOLS; // 15 rows

    auto eRow4 = [&](const F4& a, const F4& b, const F4& cc, const F4& d,
                     const F10& x2r, const F4& x1r) -> F4 {
        F4 e;
        #pragma unroll
        for (int q = 0; q < 4; ++q) {
            const float e1 = x1r.v[q] + C * (cc.v[q] - b.v[q])
                                      - C * (x2r.v[q + 3] - x2r.v[q + 2]);
            e.v[q] = e1
                + C * (f0 * a.v[q] + f1 * b.v[q] + f2 * cc.v[q] + f3 * d.v[q])
                - C * (f0 * x2r.v[q + 1] + f1 * x2r.v[q + 2]
                     + f2 * x2r.v[q + 3] + f3 * x2r.v[q + 4]);
        }
        if (gL) {
            e.v[0] = x1r.v[0];
            e.v[1] = x1r.v[1] + C * (cc.v[1] - b.v[1])
                              - C * (x2r.v[4] - x2r.v[3]);
        }
        if (gR) {
            e.v[3] = x1r.v[3];
            e.v[2] = x1r.v[2] + C * (cc.v[2] - b.v[2])
                              - C * (x2r.v[5] - x2r.v[4]);
        }
        return e;
    };

    // ---- compute one output row r (0..11): tile reads T3[r..r+6],
    // T2[r..r+3], T1[r..r+3] (r12's verified row math) ----
    auto computeRow = [&](int r) {
        const int i = i0 + r;

        const F4  x3m3 = lb4(&T3[(r    ) * LCOLS], lc);
        const F7  x3m2 = l7 (&T3[(r + 1) * LCOLS], lc);
        const F7  x3m1 = l7 (&T3[(r + 2) * LCOLS], lc);
        const F7  x3i  = l7 (&T3[(r + 3) * LCOLS], lc);
        const F7  x3p1 = l7 (&T3[(r + 4) * LCOLS], lc);
        const F4  x3p2 = lb4(&T3[(r + 5) * LCOLS], lc);
        const F4  x3p3 = lb4(&T3[(r + 6) * LCOLS], lc);

        const F10 x2m1 = l10(&T2[(r    ) * LCOLS], lc);
        const F10 x2i  = l10(&T2[(r + 1) * LCOLS], lc);
        const F10 x2p1 = l10(&T2[(r + 2) * LCOLS], lc);
        const F10 x2p2 = l10(&T2[(r + 3) * LCOLS], lc);

        const F4  x1m1 = lb4(&T1[(r    ) * LCOLS], lc);
        const F7  x1i  = l7 (&T1[(r + 1) * LCOLS], lc);
        const F4  x1p1 = lb4(&T1[(r + 2) * LCOLS], lc);
        const F4  x1p2 = lb4(&T1[(r + 3) * LCOLS], lc);

        // E row i, 7-wide
        F7 e7;
        #pragma unroll
        for (int m = 0; m < 7; ++m) {
            const float e1 = x1i.v[m] + C * (x3i.v[m] - x3m1.v[m])
                                      - C * (x2i.v[m + 2] - x2i.v[m + 1]);
            e7.v[m] = e1
                + C * (f0 * x3m2.v[m] + f1 * x3m1.v[m] + f2 * x3i.v[m] + f3 * x3p1.v[m])
                - C * (f0 * x2i.v[m] + f1 * x2i.v[m + 1] + f2 * x2i.v[m + 2] + f3 * x2i.v[m + 3]);
        }
        if (gL) {
            e7.v[1] = x1i.v[1];
            e7.v[2] = x1i.v[2] + C * (x3i.v[2] - x3m1.v[2])
                               - C * (x2i.v[4] - x2i.v[3]);
        }
        if (gR) {
            e7.v[4] = x1i.v[4];
            e7.v[3] = x1i.v[3] + C * (x3i.v[3] - x3m1.v[3])
                               - C * (x2i.v[5] - x2i.v[4]);
        }

        const F4 em1 = eRow4(x3m3,      mid(x3m2), mid(x3m1), mid(x3i), x2m1, x1m1);
        const F4 ep1 = eRow4(mid(x3m1), mid(x3i),  mid(x3p1), x3p2,     x2p1, x1p1);
        const F4 ep2 = eRow4(mid(x3i),  mid(x3p1), x3p2,      x3p3,     x2p2, x1p2);

        float hx[4], hy[4];
        #pragma unroll
        for (int q = 0; q < 4; ++q) {
            hx[q] = x2i.v[q + 3] - C * (x1i.v[q + 2] - x1i.v[q + 1])
                  - C * (f0 * e7.v[q] + f1 * e7.v[q + 1]
                       + f2 * e7.v[q + 2] + f3 * e7.v[q + 3]);
            hy[q] = x3i.v[q + 1] + C * (x1p1.v[q] - x1i.v[q + 1])
                  + C * (f0 * em1.v[q] + f1 * e7.v[q + 1]
                       + f2 * ep1.v[q] + f3 * ep2.v[q]);
        }
        if (gL) {
            hx[0] = x2i.v[3] - C * (x1i.v[2] - x1i.v[1]);
            hy[0] = x3i.v[1];
            hy[1] = x3i.v[2] + C * (x1p1.v[1] - x1i.v[2]);
        }
        if (gR) {
            hx[3] = x2i.v[6];
            hy[3] = x3i.v[4];
            hx[2] = x2i.v[5] - C * (x1i.v[4] - x1i.v[3]);
            hy[2] = x3i.v[3] + C * (x1p1.v[2] - x1i.v[3]);
        }

        const size_t idx = (size_t)i * NYg + col0 + 4 * cq;
        *(float4*)(E  + idx) = make_float4(e7.v[1], e7.v[2], e7.v[3], e7.v[4]);
        *(float4*)(Hx + idx) = make_float4(hx[0], hx[1], hx[2], hx[3]);
        *(float4*)(Hy + idx) = make_float4(hy[0], hy[1], hy[2], hy[3]);
    };

    computeRow(g);
    computeRow(g + 4);
    computeRow(g + 8);
}

// ---------------------------------------------------------------------------
// Edge kernel: boundary row bands [0,7] and [4088,4095], fully guarded.
// ---------------------------------------------------------------------------
#define TRE 8
#define EROWSE 12
#define ECOLSE 136

__global__ __launch_bounds__(256) void edge_kernel(
    const float* __restrict__ X1, const float* __restrict__ X2,
    const float* __restrict__ X3, const float* __restrict__ w1,
    float* __restrict__ E, float* __restrict__ Hx, float* __restrict__ Hy)
{
    __shared__ float elds[EROWSE][ECOLSE];
    const int t    = threadIdx.x;
    const int row0 = blockIdx.y ? (NXg - TRE) : 0;
    const int col0 = blockIdx.x * 128;

    const float wv = w1[0];
    const float f0 = (wv - 1.0f) / 3.0f;
    const float f1 = -wv;
    const float f2 = wv;
    const float f3 = (1.0f - wv) / 3.0f;

    for (int cidx = t; cidx < EROWSE * ECOLSE; cidx += 256) {
        const int r  = cidx / ECOLSE;
        const int cc = cidx - r * ECOLSE;
        const int gr = row0 - 2 + r;
        const int gc = col0 - 4 + cc;
        float e = 0.0f;
        if (gr >= 0 && gr < NXg && gc >= 0 && gc < NYg) {
            const size_t idx = (size_t)gr * NYg + gc;
            const float x1 = X1[idx];
            if (gr == 0 || gr == NXg - 1 || gc == 0 || gc == NYg - 1) {
                e = x1;
            } else {
                float e1 = x1 + C * (X3[idx] - X3[idx - NYg])
                              - C * (X2[idx] - X2[idx - 1]);
                if (gr >= 2 && gr <= NXg - 3 && gc >= 2 && gc <= NYg - 3) {
                    e1 += C * (f0 * X3[idx - 2 * NYg] + f1 * X3[idx - NYg]
                             + f2 * X3[idx] + f3 * X3[idx + NYg])
                        - C * (f0 * X2[idx - 2] + f1 * X2[idx - 1]
                             + f2 * X2[idx] + f3 * X2[idx + 1]);
                }
                e = e1;
            }
        }
        elds[r][cc] = e;
    }
    __syncthreads();

    for (int cidx = t; cidx < TRE * 128; cidx += 256) {
        const int hr  = cidx >> 7;
        const int tc  = cidx & 127;
        const int gr  = row0 + hr;
        const int gcc = col0 + tc;
        const size_t idx = (size_t)gr * NYg + gcc;
        const int lr  = hr + 2;
        const int lc2 = tc + 4;

        const float ec = elds[lr][lc2];
        E[idx] = ec;

        const float x1 = X1[idx];

        float hx = X2[idx];
        if (gr >= 1 && gr <= NXg - 2 && gcc <= NYg - 2)
            hx -= C * (X1[idx + 1] - x1);
        if (gr >= 2 && gr <= NXg - 3 && gcc >= 1 && gcc <= NYg - 3) {
            hx -= C * (f0 * elds[lr][lc2 - 1] + f1 * ec
                     + f2 * elds[lr][lc2 + 1] + f3 * elds[lr][lc2 + 2]);
        }
        Hx[idx] = hx;

        float hy = X3[idx];
        if (gr <= NXg - 2 && gcc >= 1 && gcc <= NYg - 2)
            hy += C * (X1[idx + NYg] - x1);
        if (gr >= 1 && gr <= NXg - 3 && gcc >= 2 && gcc <= NYg - 3) {
            hy += C * (f0 * elds[lr - 1][lc2] + f1 * ec
                     + f2 * elds[lr + 1][lc2] + f3 * elds[lr + 2][lc2]);
        }
        Hy[idx] = hy;
    }
}

extern "C" void kernel_launch(void* const* d_in, const int* in_sizes, int n_in,
                              void* d_out, int out_size, void* d_ws, size_t ws_size,
                              hipStream_t stream) {
    const float* X1 = (const float*)d_in[0];
    const float* X2 = (const float*)d_in[1];
    const float* X3 = (const float*)d_in[2];
    const float* w1 = (const float*)d_in[3];

    float* E  = (float*)d_out;
    float* Hx = (float*)d_out + (size_t)NXg * NYg;
    float* Hy = (float*)d_out + 2 * (size_t)NXg * NYg;

    edge_kernel<<<dim3(32, 2), 256, 0, stream>>>(X1, X2, X3, w1, E, Hx, Hy);
    band_kernel<<<dim3(NPANEL, NBANDS), 256, 0, stream>>>(X1, X2, X3, w1, E, Hx, Hy);
}